// Round 7
// baseline (231.865 us; speedup 1.0000x reference)
//
#include <hip/hip_runtime.h>
#include <cstdint>
#include <cstddef>

#define THETA 1.2f
#define XI 0.3f
#define BDIM 8192
#define DDIM 512
#define NWORK 2112         // live blocks: sum_p (32 - p/4), p in 0..127

typedef float f32x4 __attribute__((ext_vector_type(4)));
typedef int i32x8 __attribute__((ext_vector_type(8)));

// Kernel 1: per-row L2 normalize fp32 -> fp8 e4m3, coalesced loads/stores.
// One wave per row; lane l owns floats 4l..4l+3 and 256+4l..256+4l+3.
__global__ __launch_bounds__(256) void normalize_rows(
    const float* __restrict__ x, unsigned char* __restrict__ nf8,
    float* __restrict__ sq, unsigned int* __restrict__ counter)
{
    if (blockIdx.x == 0 && threadIdx.x == 0) { *counter = 0u; }
    int row = blockIdx.x * 4 + (threadIdx.x >> 6);
    int l = threadIdx.x & 63;
    const float4* xr = (const float4*)(x + (size_t)row * DDIM);
    float4 f0 = xr[l];        // floats 4l..4l+3       (coalesced)
    float4 f1 = xr[l + 64];   // floats 256+4l..+3     (coalesced)
    float s = f0.x*f0.x + f0.y*f0.y + f0.z*f0.z + f0.w*f0.w
            + f1.x*f1.x + f1.y*f1.y + f1.z*f1.z + f1.w*f1.w;
    #pragma unroll
    for (int m = 1; m < 64; m <<= 1) s += __shfl_xor(s, m);
    float rn = rsqrtf(s);
    int pk0 = __builtin_amdgcn_cvt_pk_fp8_f32(f0.x * rn, f0.y * rn, 0, false);
    pk0     = __builtin_amdgcn_cvt_pk_fp8_f32(f0.z * rn, f0.w * rn, pk0, true);
    int pk1 = __builtin_amdgcn_cvt_pk_fp8_f32(f1.x * rn, f1.y * rn, 0, false);
    pk1     = __builtin_amdgcn_cvt_pk_fp8_f32(f1.z * rn, f1.w * rn, pk1, true);
    int* rowp = (int*)(nf8 + (size_t)row * DDIM);
    rowp[l] = pk0;            // bytes k=4l..4l+3      (coalesced)
    rowp[l + 64] = pk1;       // bytes k=256+4l..+3    (coalesced)
    if (l == 0) sq[row] = s * rn * rn;
}

// Kernel 2: grid (128,32). Block = i-panel p (64 rows) x j-group g (256 cols).
// A-panel (64x512 fp8 = 32 KB) staged to LDS once (granule-swizzled, one barrier).
// Each wave computes an independent 64x64 tile (jc = g*256 + w*64) with
// mfma_scale_f32_16x16x128_f8f6f4; B fragments direct from L2-hot global.
// launch_bounds(256,2): big register budget -> no spills, compiler can pipeline.
__global__ __launch_bounds__(256, 2) void gram_hinge(
    const unsigned char* __restrict__ nf8, const float* __restrict__ sq,
    const int* __restrict__ y, double* __restrict__ part,
    unsigned int* __restrict__ counter, float* __restrict__ out)
{
    int p = blockIdx.x;              // i-panel, rows p*64 .. p*64+63
    int g = blockIdx.y;              // j-group, cols g*256 .. +255
    int a = p >> 2;
    if (g < a) return;               // whole block below diagonal

    __shared__ unsigned char As[64 * 512];   // 32 KB
    __shared__ float wpart[4];
    __shared__ double dpart[4];
    __shared__ int is_last;

    int tid = threadIdx.x;
    int w = tid >> 6, l = tid & 63;
    int lr = l & 15, q = l >> 4;

    // ---- stage A-panel: 8 DMA instrs/wave, each 1 KB contiguous (2 rows) ----
    const unsigned char* gA = nf8 + (size_t)p * 64 * DDIM;
    {
        int rl = l >> 5;             // 0/1: which row of the segment pair
        int gl = l & 31;             // LDS granule within row
        #pragma unroll
        for (int i = 0; i < 8; ++i) {
            int s = i * 4 + w;       // segment 0..31 (2 rows each), wave-uniform
            int r = s * 2 + rl;
            int gg = gl ^ (r & 7);   // fetch swizzled global granule -> linear LDS
            __builtin_amdgcn_global_load_lds(
                (const __attribute__((address_space(1))) void*)
                    (gA + (size_t)s * 1024 + rl * 512 + gg * 16),
                (__attribute__((address_space(3))) void*)(As + s * 1024), 16, 0, 0);
        }
    }
    __syncthreads();   // single drain+barrier per block

    int jc = g * 256 + w * 64;       // this wave's j-tile origin
    bool live = (jc >= p * 64);      // wave-uniform: tile intersects upper triangle
    float local = 0.f;

    if (live) {
        f32x4 accv[4][4] = {};
        const unsigned char* rowB = nf8 + (size_t)(jc + lr) * DDIM + q * 32;

        #pragma unroll
        for (int it = 0; it < 4; ++it) {
            int k0 = it * 128;
            i32x8 af[4], bfr[4];
            // A from LDS: row r=mi*16+lr, granules (it*8+q*2)|{0,1} ^ (r&7)
            #pragma unroll
            for (int mi = 0; mi < 4; ++mi) {
                int r = mi * 16 + lr;
                int G0 = it * 8 + q * 2;
                int sw = r & 7;
                int4 a0 = *(const int4*)(As + r * 512 + ((G0 ^ sw) << 4));
                int4 a1 = *(const int4*)(As + r * 512 + (((G0 | 1) ^ sw) << 4));
                af[mi][0] = a0.x; af[mi][1] = a0.y; af[mi][2] = a0.z; af[mi][3] = a0.w;
                af[mi][4] = a1.x; af[mi][5] = a1.y; af[mi][6] = a1.z; af[mi][7] = a1.w;
            }
            // B direct from global (L2-hot)
            #pragma unroll
            for (int ni = 0; ni < 4; ++ni) {
                const int4* bp = (const int4*)(rowB + (size_t)ni * 16 * DDIM + k0);
                int4 b0 = bp[0], b1 = bp[1];
                bfr[ni][0] = b0.x; bfr[ni][1] = b0.y; bfr[ni][2] = b0.z; bfr[ni][3] = b0.w;
                bfr[ni][4] = b1.x; bfr[ni][5] = b1.y; bfr[ni][6] = b1.z; bfr[ni][7] = b1.w;
            }
            #pragma unroll
            for (int mi = 0; mi < 4; ++mi)
                #pragma unroll
                for (int ni = 0; ni < 4; ++ni)
                    accv[mi][ni] = __builtin_amdgcn_mfma_scale_f32_16x16x128_f8f6f4(
                        af[mi], bfr[ni], accv[mi][ni],
                        0, 0, 0, 0x7F7F7F7F, 0, 0x7F7F7F7F);
        }

        // Epilogue: C/D layout col(lane&15)=j, row(q*4+reg)=i (validated R0-R6).
        int jbase = jc + lr;
        float sqj[4]; int yj[4];
        #pragma unroll
        for (int ni = 0; ni < 4; ++ni) {
            int gj = jbase + ni * 16;
            sqj[ni] = sq[gj]; yj[ni] = y[gj];
        }
        #pragma unroll
        for (int mi = 0; mi < 4; ++mi) {
            #pragma unroll
            for (int r = 0; r < 4; ++r) {
                int gi = p * 64 + mi * 16 + q * 4 + r;
                float sqi = sq[gi]; int yi = y[gi];
                #pragma unroll
                for (int ni = 0; ni < 4; ++ni) {
                    int gj = jbase + ni * 16;
                    float G = accv[mi][ni][r];
                    float d2 = sqi + sqj[ni] - 2.0f * G;
                    float h = fmaxf(THETA - d2, 0.0f);
                    float tv = XI + ((yi == yj[ni]) ? h : -h);
                    if (gj >= gi) local += tv;   // filters only on the diagonal tile
                }
            }
        }
    }

    #pragma unroll
    for (int off = 32; off > 0; off >>= 1) local += __shfl_down(local, off);
    if (l == 0) wpart[w] = local;
    __syncthreads();
    if (tid == 0) {
        // compact live-block index: cum(p) + (g - a)
        int b = p & 3;
        int idx = 32 * p - (2 * a * (a - 1) + a * b) + (g - a);
        double ssum = (double)wpart[0] + (double)wpart[1]
                    + (double)wpart[2] + (double)wpart[3];
        __hip_atomic_store(&part[idx], ssum, __ATOMIC_RELEASE, __HIP_MEMORY_SCOPE_AGENT);
        unsigned int ticket = __hip_atomic_fetch_add(
            counter, 1u, __ATOMIC_ACQ_REL, __HIP_MEMORY_SCOPE_AGENT);
        is_last = (ticket == NWORK - 1) ? 1 : 0;
    }
    __syncthreads();
    if (is_last) {
        double s = 0.0;
        for (int i = tid; i < NWORK; i += 256)
            s += __hip_atomic_load(&part[i], __ATOMIC_ACQUIRE, __HIP_MEMORY_SCOPE_AGENT);
        #pragma unroll
        for (int off = 32; off > 0; off >>= 1) s += __shfl_down(s, off);
        if (l == 0) dpart[w] = s;
        __syncthreads();
        if (tid == 0) {
            const double m = 1.0 / ((double)BDIM * (double)BDIM - (double)BDIM);
            out[0] = (float)((dpart[0] + dpart[1] + dpart[2] + dpart[3]) * m);
        }
    }
}

extern "C" void kernel_launch(void* const* d_in, const int* in_sizes, int n_in,
                              void* d_out, int out_size, void* d_ws, size_t ws_size,
                              hipStream_t stream) {
    const float* x = (const float*)d_in[0];
    const int* y = (const int*)d_in[1];
    float* out = (float*)d_out;

    unsigned char* nf8 = (unsigned char*)d_ws;                          // 4 MB fp8
    char* p = (char*)d_ws + (size_t)BDIM * DDIM;
    float* sq = (float*)p;                                              // 32 KB
    unsigned int* counter = (unsigned int*)(p + (size_t)BDIM * 4);
    double* part = (double*)(p + (size_t)BDIM * 4 + 64);                // NWORK doubles

    normalize_rows<<<BDIM / 4, 256, 0, stream>>>(x, nf8, sq, counter);
    gram_hinge<<<dim3(128, 32), 256, 0, stream>>>(nf8, sq, y, part, counter, out);
}

// Round 8
// 135.723 us; speedup vs baseline: 1.7084x; 1.7084x over previous
//
#include <hip/hip_runtime.h>
#include <cstdint>
#include <cstddef>

#define THETA 1.2f
#define XI 0.3f
#define BDIM 8192
#define DDIM 512
#define NWORK 544          // sum_{jg=0..15} (4*jg+4) blocks (jg-major triangular)

typedef float f32x4 __attribute__((ext_vector_type(4)));
typedef int i32x8 __attribute__((ext_vector_type(8)));

// Kernel 1: per-row L2 normalize fp32 -> fp8 e4m3, coalesced; sq[row]=||n||^2; zero counter.
__global__ __launch_bounds__(256) void normalize_rows(
    const float* __restrict__ x, unsigned char* __restrict__ nf8,
    float* __restrict__ sq, unsigned int* __restrict__ counter)
{
    if (blockIdx.x == 0 && threadIdx.x == 0) { *counter = 0u; }
    int row = blockIdx.x * 4 + (threadIdx.x >> 6);
    int l = threadIdx.x & 63;
    const float4* xr = (const float4*)(x + (size_t)row * DDIM);
    float4 f0 = xr[l];
    float4 f1 = xr[l + 64];
    float s = f0.x*f0.x + f0.y*f0.y + f0.z*f0.z + f0.w*f0.w
            + f1.x*f1.x + f1.y*f1.y + f1.z*f1.z + f1.w*f1.w;
    #pragma unroll
    for (int m = 1; m < 64; m <<= 1) s += __shfl_xor(s, m);
    float rn = rsqrtf(s);
    int pk0 = __builtin_amdgcn_cvt_pk_fp8_f32(f0.x * rn, f0.y * rn, 0, false);
    pk0     = __builtin_amdgcn_cvt_pk_fp8_f32(f0.z * rn, f0.w * rn, pk0, true);
    int pk1 = __builtin_amdgcn_cvt_pk_fp8_f32(f1.x * rn, f1.y * rn, 0, false);
    pk1     = __builtin_amdgcn_cvt_pk_fp8_f32(f1.z * rn, f1.w * rn, pk1, true);
    int* rowp = (int*)(nf8 + (size_t)row * DDIM);
    rowp[l] = pk0;
    rowp[l + 64] = pk1;
    if (l == 0) sq[row] = s * rn * rn;
}

// Kernel 2: R6 structure (A-panel 128x512 = 64 KB LDS staged once, 4 j-tiles/block,
// waves 2x2 per 128x128 tile, mfma_scale 16x16x128 fp8) with two deltas:
//  (a) jg-MAJOR block order: co-launched blocks share the same 256-KB B-set -> L2-hot B.
//  (b) register double-buffered B fragments: prefetch it+1's B before it's MFMAs.
// LDS kept at 64 KB on purpose: pins compiler at 2 blocks/CU, no spill (R7 lesson).
__global__ __launch_bounds__(256) void gram_hinge(
    const unsigned char* __restrict__ nf8, const float* __restrict__ sq,
    const int* __restrict__ y, double* __restrict__ part,
    unsigned int* __restrict__ counter, float* __restrict__ out)
{
    // jg-major decode, reversed so large-jg groups launch first:
    // u in [2*jg*(jg+1), 2*(jg+1)*(jg+2)) -> (jg, bi = u - 2*jg*(jg+1)), bi in 0..4*jg+3
    int u = (NWORK - 1) - (int)blockIdx.x;
    int jg = (int)((sqrtf(1.0f + 2.0f * (float)u) - 1.0f) * 0.5f);
    while (2 * (jg + 1) * (jg + 2) <= u) ++jg;
    while (2 * jg * (jg + 1) > u) --jg;
    int bi = u - 2 * jg * (jg + 1);

    __shared__ unsigned char As[128 * 512];   // 64 KB A-panel, granule-swizzled rows
    __shared__ float wpart[4];
    __shared__ double dpart[4];
    __shared__ int is_last;

    int tid = threadIdx.x;
    int w = tid >> 6, l = tid & 63;
    int wr = w >> 1, wc = w & 1;     // wave 2x2 -> 64x64 per 128x128 tile
    int lr = l & 15, q = l >> 4;

    // ---- stage A-panel once: 16 DMA instrs/wave, each 1 KB contiguous (2 rows) ----
    const unsigned char* gA = nf8 + (size_t)bi * 128 * DDIM;
    {
        int rl = l >> 5;             // which row of the pair
        int gl = l & 31;             // LDS granule within row
        #pragma unroll
        for (int i = 0; i < 16; ++i) {
            int rbase = w * 32 + i * 2;
            int r = rbase + rl;
            int gg = gl ^ (r & 7);   // in-row 16-B granule swizzle (coalescing-safe)
            __builtin_amdgcn_global_load_lds(
                (const __attribute__((address_space(1))) void*)(gA + (size_t)r * DDIM + gg * 16),
                (__attribute__((address_space(3))) void*)(As + rbase * 512), 16, 0, 0);
        }
    }
    __syncthreads();   // single drain+barrier per block

    float local = 0.f;

    for (int jt = 0; jt < 4; ++jt) {
        int bj = jg * 4 + jt;
        if (bj < bi) continue;       // wave-uniform skip below diagonal

        f32x4 accv[4][4] = {};
        const unsigned char* rowB =
            nf8 + ((size_t)(bj * 128 + wc * 64 + lr)) * DDIM + q * 32;

        i32x8 bfr[2][4];
        // preload it=0 B fragments
        #pragma unroll
        for (int ni = 0; ni < 4; ++ni) {
            const int4* bp = (const int4*)(rowB + (size_t)ni * 16 * DDIM);
            int4 b0 = bp[0], b1 = bp[1];
            bfr[0][ni][0] = b0.x; bfr[0][ni][1] = b0.y; bfr[0][ni][2] = b0.z; bfr[0][ni][3] = b0.w;
            bfr[0][ni][4] = b1.x; bfr[0][ni][5] = b1.y; bfr[0][ni][6] = b1.z; bfr[0][ni][7] = b1.w;
        }

        #pragma unroll
        for (int it = 0; it < 4; ++it) {
            int cur = it & 1, nxt = cur ^ 1;
            // prefetch next K-iter's B before this iter's MFMAs
            if (it < 3) {
                int k1 = (it + 1) * 128;
                #pragma unroll
                for (int ni = 0; ni < 4; ++ni) {
                    const int4* bp = (const int4*)(rowB + (size_t)ni * 16 * DDIM + k1);
                    int4 b0 = bp[0], b1 = bp[1];
                    bfr[nxt][ni][0] = b0.x; bfr[nxt][ni][1] = b0.y;
                    bfr[nxt][ni][2] = b0.z; bfr[nxt][ni][3] = b0.w;
                    bfr[nxt][ni][4] = b1.x; bfr[nxt][ni][5] = b1.y;
                    bfr[nxt][ni][6] = b1.z; bfr[nxt][ni][7] = b1.w;
                }
            }
            // A fragments from LDS (granule-swizzled)
            i32x8 af[4];
            #pragma unroll
            for (int mi = 0; mi < 4; ++mi) {
                int r = wr * 64 + mi * 16 + lr;
                int G0 = it * 8 + q * 2;
                int sw = r & 7;
                int4 a0 = *(const int4*)(As + r * 512 + ((G0 ^ sw) << 4));
                int4 a1 = *(const int4*)(As + r * 512 + (((G0 | 1) ^ sw) << 4));
                af[mi][0] = a0.x; af[mi][1] = a0.y; af[mi][2] = a0.z; af[mi][3] = a0.w;
                af[mi][4] = a1.x; af[mi][5] = a1.y; af[mi][6] = a1.z; af[mi][7] = a1.w;
            }
            #pragma unroll
            for (int mi = 0; mi < 4; ++mi)
                #pragma unroll
                for (int ni = 0; ni < 4; ++ni)
                    accv[mi][ni] = __builtin_amdgcn_mfma_scale_f32_16x16x128_f8f6f4(
                        af[mi], bfr[cur][ni], accv[mi][ni],
                        0, 0, 0, 0x7F7F7F7F, 0, 0x7F7F7F7F);
        }

        // Epilogue: C/D layout col=lane&15 (j), row=q*4+reg (i).
        int jbase = bj * 128 + wc * 64 + lr;
        float sqj[4]; int yj[4];
        #pragma unroll
        for (int ni = 0; ni < 4; ++ni) {
            int gj = jbase + ni * 16;
            sqj[ni] = sq[gj]; yj[ni] = y[gj];
        }
        #pragma unroll
        for (int mi = 0; mi < 4; ++mi) {
            #pragma unroll
            for (int r = 0; r < 4; ++r) {
                int gi = bi * 128 + wr * 64 + mi * 16 + q * 4 + r;
                float sqi = sq[gi]; int yi = y[gi];
                #pragma unroll
                for (int ni = 0; ni < 4; ++ni) {
                    int gj = jbase + ni * 16;
                    float G = accv[mi][ni][r];
                    float d2 = sqi + sqj[ni] - 2.0f * G;
                    float h = fmaxf(THETA - d2, 0.0f);
                    float tv = XI + ((yi == yj[ni]) ? h : -h);
                    if (gj >= gi) local += tv;
                }
            }
        }
    }

    #pragma unroll
    for (int off = 32; off > 0; off >>= 1) local += __shfl_down(local, off);
    if (l == 0) wpart[w] = local;
    __syncthreads();
    if (tid == 0) {
        double ssum = (double)wpart[0] + (double)wpart[1]
                    + (double)wpart[2] + (double)wpart[3];
        __hip_atomic_store(&part[blockIdx.x], ssum, __ATOMIC_RELEASE, __HIP_MEMORY_SCOPE_AGENT);
        unsigned int ticket = __hip_atomic_fetch_add(
            counter, 1u, __ATOMIC_ACQ_REL, __HIP_MEMORY_SCOPE_AGENT);
        is_last = (ticket == NWORK - 1) ? 1 : 0;
    }
    __syncthreads();
    if (is_last) {
        double s = 0.0;
        for (int i = tid; i < NWORK; i += 256)
            s += __hip_atomic_load(&part[i], __ATOMIC_ACQUIRE, __HIP_MEMORY_SCOPE_AGENT);
        #pragma unroll
        for (int off = 32; off > 0; off >>= 1) s += __shfl_down(s, off);
        if (l == 0) dpart[w] = s;
        __syncthreads();
        if (tid == 0) {
            const double m = 1.0 / ((double)BDIM * (double)BDIM - (double)BDIM);
            out[0] = (float)((dpart[0] + dpart[1] + dpart[2] + dpart[3]) * m);
        }
    }
}

extern "C" void kernel_launch(void* const* d_in, const int* in_sizes, int n_in,
                              void* d_out, int out_size, void* d_ws, size_t ws_size,
                              hipStream_t stream) {
    const float* x = (const float*)d_in[0];
    const int* y = (const int*)d_in[1];
    float* out = (float*)d_out;

    unsigned char* nf8 = (unsigned char*)d_ws;                          // 4 MB fp8
    char* p = (char*)d_ws + (size_t)BDIM * DDIM;
    float* sq = (float*)p;                                              // 32 KB
    unsigned int* counter = (unsigned int*)(p + (size_t)BDIM * 4);
    double* part = (double*)(p + (size_t)BDIM * 4 + 64);                // NWORK doubles

    normalize_rows<<<BDIM / 4, 256, 0, stream>>>(x, nf8, sq, counter);
    gram_hinge<<<NWORK, 256, 0, stream>>>(nf8, sq, y, part, counter, out);
}

// Round 10
// 129.147 us; speedup vs baseline: 1.7954x; 1.0509x over previous
//
#include <hip/hip_runtime.h>
#include <cstdint>
#include <cstddef>

#define THETA 1.2f
#define XI 0.3f
#define BDIM 8192
#define DDIM 512
#define NWORK 544          // jg-major triangular tiles: sum_{jg=0..15}(4*jg+4)
// upper-triangle-with-diagonal pair count: B*(B+1)/2
#define NPAIRS_UP (((double)BDIM * (double)(BDIM + 1)) * 0.5)

typedef float f32x4 __attribute__((ext_vector_type(4)));
typedef int i32x8 __attribute__((ext_vector_type(8)));

// Kernel 1: per-row L2 normalize fp32 -> fp8 e4m3, coalesced; sq[row]=||n||^2; zero counter.
__global__ __launch_bounds__(256) void normalize_rows(
    const float* __restrict__ x, unsigned char* __restrict__ nf8,
    float* __restrict__ sq, unsigned int* __restrict__ counter)
{
    if (blockIdx.x == 0 && threadIdx.x == 0) { *counter = 0u; }
    int row = blockIdx.x * 4 + (threadIdx.x >> 6);
    int l = threadIdx.x & 63;
    const float4* xr = (const float4*)(x + (size_t)row * DDIM);
    float4 f0 = xr[l];
    float4 f1 = xr[l + 64];
    float s = f0.x*f0.x + f0.y*f0.y + f0.z*f0.z + f0.w*f0.w
            + f1.x*f1.x + f1.y*f1.y + f1.z*f1.z + f1.w*f1.w;
    #pragma unroll
    for (int m = 1; m < 64; m <<= 1) s += __shfl_xor(s, m);
    float rn = rsqrtf(s);
    int pk0 = __builtin_amdgcn_cvt_pk_fp8_f32(f0.x * rn, f0.y * rn, 0, false);
    pk0     = __builtin_amdgcn_cvt_pk_fp8_f32(f0.z * rn, f0.w * rn, pk0, true);
    int pk1 = __builtin_amdgcn_cvt_pk_fp8_f32(f1.x * rn, f1.y * rn, 0, false);
    pk1     = __builtin_amdgcn_cvt_pk_fp8_f32(f1.z * rn, f1.w * rn, pk1, true);
    int* rowp = (int*)(nf8 + (size_t)row * DDIM);
    rowp[l] = pk0;
    rowp[l + 64] = pk1;
    if (l == 0) sq[row] = s * rn * rn;
}

// Kernel 2: R8 K-loop unchanged (64-KB A-panel LDS staged once, jg-major order,
// register-double-buffered B, mfma_scale 16x16x128 fp8). Epilogue overhauled:
// sq/y staged to LDS, XI accumulated analytically, diag/off-diag specialization,
// 4 independent accumulators.
__global__ __launch_bounds__(256) void gram_hinge(
    const unsigned char* __restrict__ nf8, const float* __restrict__ sq,
    const int* __restrict__ y, double* __restrict__ part,
    unsigned int* __restrict__ counter, float* __restrict__ out)
{
    // jg-major decode, reversed: large jg (big B-sets) first
    int u = (NWORK - 1) - (int)blockIdx.x;
    int jg = (int)((sqrtf(1.0f + 2.0f * (float)u) - 1.0f) * 0.5f);
    while (2 * (jg + 1) * (jg + 2) <= u) ++jg;
    while (2 * jg * (jg + 1) > u) --jg;
    int bi = u - 2 * jg * (jg + 1);

    __shared__ unsigned char As[128 * 512];   // 64 KB A-panel, granule-swizzled rows
    __shared__ float sqA[128];
    __shared__ int   yA[128];
    __shared__ float sqB[512];
    __shared__ int   yB[512];
    __shared__ float wpart[4];
    __shared__ double dpart[4];
    __shared__ int is_last;

    int tid = threadIdx.x;
    int w = tid >> 6, l = tid & 63;
    int wr = w >> 1, wc = w & 1;     // wave 2x2 -> 64x64 per 128x128 tile
    int lr = l & 15, q = l >> 4;

    // ---- stage A-panel once: 16 DMA instrs/wave, each 1 KB contiguous (2 rows) ----
    const unsigned char* gA = nf8 + (size_t)bi * 128 * DDIM;
    {
        int rl = l >> 5;
        int gl = l & 31;
        #pragma unroll
        for (int i = 0; i < 16; ++i) {
            int rbase = w * 32 + i * 2;
            int r = rbase + rl;
            int gg = gl ^ (r & 7);   // in-row 16-B granule swizzle (coalescing-safe)
            __builtin_amdgcn_global_load_lds(
                (const __attribute__((address_space(1))) void*)(gA + (size_t)r * DDIM + gg * 16),
                (__attribute__((address_space(3))) void*)(As + rbase * 512), 16, 0, 0);
        }
    }
    // ---- stage sq/y for A-rows and the whole 512-col B group (coalesced) ----
    {
        int arow = bi * 128;
        if (tid < 128) { sqA[tid] = sq[arow + tid]; yA[tid] = y[arow + tid]; }
        int cb = jg * 512;
        sqB[tid]       = sq[cb + tid];
        sqB[tid + 256] = sq[cb + tid + 256];
        yB[tid]        = y[cb + tid];
        yB[tid + 256]  = y[cb + tid + 256];
    }
    __syncthreads();   // single drain+barrier per block

    float acc0 = 0.f, acc1 = 0.f, acc2 = 0.f, acc3 = 0.f;

    for (int jt = 0; jt < 4; ++jt) {
        int bj = jg * 4 + jt;
        if (bj < bi) continue;       // wave-uniform skip below diagonal

        f32x4 accv[4][4] = {};
        const unsigned char* rowB =
            nf8 + ((size_t)(bj * 128 + wc * 64 + lr)) * DDIM + q * 32;

        i32x8 bfr[2][4];
        #pragma unroll
        for (int ni = 0; ni < 4; ++ni) {
            const int4* bp = (const int4*)(rowB + (size_t)ni * 16 * DDIM);
            int4 b0 = bp[0], b1 = bp[1];
            bfr[0][ni][0] = b0.x; bfr[0][ni][1] = b0.y; bfr[0][ni][2] = b0.z; bfr[0][ni][3] = b0.w;
            bfr[0][ni][4] = b1.x; bfr[0][ni][5] = b1.y; bfr[0][ni][6] = b1.z; bfr[0][ni][7] = b1.w;
        }

        #pragma unroll
        for (int it = 0; it < 4; ++it) {
            int cur = it & 1, nxt = cur ^ 1;
            if (it < 3) {
                int k1 = (it + 1) * 128;
                #pragma unroll
                for (int ni = 0; ni < 4; ++ni) {
                    const int4* bp = (const int4*)(rowB + (size_t)ni * 16 * DDIM + k1);
                    int4 b0 = bp[0], b1 = bp[1];
                    bfr[nxt][ni][0] = b0.x; bfr[nxt][ni][1] = b0.y;
                    bfr[nxt][ni][2] = b0.z; bfr[nxt][ni][3] = b0.w;
                    bfr[nxt][ni][4] = b1.x; bfr[nxt][ni][5] = b1.y;
                    bfr[nxt][ni][6] = b1.z; bfr[nxt][ni][7] = b1.w;
                }
            }
            i32x8 af[4];
            #pragma unroll
            for (int mi = 0; mi < 4; ++mi) {
                int r = wr * 64 + mi * 16 + lr;
                int G0 = it * 8 + q * 2;
                int sw = r & 7;
                int4 a0 = *(const int4*)(As + r * 512 + ((G0 ^ sw) << 4));
                int4 a1 = *(const int4*)(As + r * 512 + (((G0 | 1) ^ sw) << 4));
                af[mi][0] = a0.x; af[mi][1] = a0.y; af[mi][2] = a0.z; af[mi][3] = a0.w;
                af[mi][4] = a1.x; af[mi][5] = a1.y; af[mi][6] = a1.z; af[mi][7] = a1.w;
            }
            #pragma unroll
            for (int mi = 0; mi < 4; ++mi)
                #pragma unroll
                for (int ni = 0; ni < 4; ++ni)
                    accv[mi][ni] = __builtin_amdgcn_mfma_scale_f32_16x16x128_f8f6f4(
                        af[mi], bfr[cur][ni], accv[mi][ni],
                        0, 0, 0, 0x7F7F7F7F, 0, 0x7F7F7F7F);
        }

        // ---- Epilogue (C/D layout col=lane&15 (j), row=q*4+reg (i)) ----
        int jrow = jt * 128 + wc * 64 + lr;     // index into sqB/yB
        float sqj[4]; int yj[4];
        #pragma unroll
        for (int ni = 0; ni < 4; ++ni) {
            sqj[ni] = sqB[jrow + ni * 16];
            yj[ni]  = yB[jrow + ni * 16];
        }
        if (bj != bi) {
            // strictly above diagonal: every element counts, no index test
            #pragma unroll
            for (int mi = 0; mi < 4; ++mi) {
                #pragma unroll
                for (int r = 0; r < 4; ++r) {
                    int ia = wr * 64 + mi * 16 + q * 4 + r;
                    float ci = THETA - sqA[ia];
                    int yi = yA[ia];
                    {
                        float h0 = fmaxf(fmaf(2.f, accv[mi][0][r], ci - sqj[0]), 0.f);
                        acc0 += (yi == yj[0]) ? h0 : -h0;
                        float h1 = fmaxf(fmaf(2.f, accv[mi][1][r], ci - sqj[1]), 0.f);
                        acc1 += (yi == yj[1]) ? h1 : -h1;
                        float h2 = fmaxf(fmaf(2.f, accv[mi][2][r], ci - sqj[2]), 0.f);
                        acc2 += (yi == yj[2]) ? h2 : -h2;
                        float h3 = fmaxf(fmaf(2.f, accv[mi][3][r], ci - sqj[3]), 0.f);
                        acc3 += (yi == yj[3]) ? h3 : -h3;
                    }
                }
            }
        } else {
            // diagonal tile: count only local col >= local row
            int cl0 = wc * 64 + lr;
            #pragma unroll
            for (int mi = 0; mi < 4; ++mi) {
                #pragma unroll
                for (int r = 0; r < 4; ++r) {
                    int rl_ = wr * 64 + mi * 16 + q * 4 + r;
                    int ia = rl_;
                    float ci = THETA - sqA[ia];
                    int yi = yA[ia];
                    #pragma unroll
                    for (int ni = 0; ni < 4; ++ni) {
                        float h = fmaxf(fmaf(2.f, accv[mi][ni][r], ci - sqj[ni]), 0.f);
                        float sh = (yi == yj[ni]) ? h : -h;
                        if (cl0 + ni * 16 >= rl_) acc0 += sh;
                    }
                }
            }
        }
    }

    float local = (acc0 + acc1) + (acc2 + acc3);
    #pragma unroll
    for (int off = 32; off > 0; off >>= 1) local += __shfl_down(local, off);
    if (l == 0) wpart[w] = local;
    __syncthreads();
    if (tid == 0) {
        double ssum = (double)wpart[0] + (double)wpart[1]
                    + (double)wpart[2] + (double)wpart[3];
        __hip_atomic_store(&part[blockIdx.x], ssum, __ATOMIC_RELEASE, __HIP_MEMORY_SCOPE_AGENT);
        unsigned int ticket = __hip_atomic_fetch_add(
            counter, 1u, __ATOMIC_ACQ_REL, __HIP_MEMORY_SCOPE_AGENT);
        is_last = (ticket == NWORK - 1) ? 1 : 0;
    }
    __syncthreads();
    if (is_last) {
        double s = 0.0;
        for (int i = tid; i < NWORK; i += 256)
            s += __hip_atomic_load(&part[i], __ATOMIC_ACQUIRE, __HIP_MEMORY_SCOPE_AGENT);
        #pragma unroll
        for (int off = 32; off > 0; off >>= 1) s += __shfl_down(s, off);
        if (l == 0) dpart[w] = s;
        __syncthreads();
        if (tid == 0) {
            // add the analytically-known XI term: XI * #upper-tri pairs
            double total = (dpart[0] + dpart[1] + dpart[2] + dpart[3])
                         + (double)XI * NPAIRS_UP;
            const double m = 1.0 / ((double)BDIM * (double)BDIM - (double)BDIM);
            out[0] = (float)(total * m);
        }
    }
}

extern "C" void kernel_launch(void* const* d_in, const int* in_sizes, int n_in,
                              void* d_out, int out_size, void* d_ws, size_t ws_size,
                              hipStream_t stream) {
    const float* x = (const float*)d_in[0];
    const int* y = (const int*)d_in[1];
    float* out = (float*)d_out;

    unsigned char* nf8 = (unsigned char*)d_ws;                          // 4 MB fp8
    char* p = (char*)d_ws + (size_t)BDIM * DDIM;
    float* sq = (float*)p;                                              // 32 KB
    unsigned int* counter = (unsigned int*)(p + (size_t)BDIM * 4);
    double* part = (double*)(p + (size_t)BDIM * 4 + 64);                // NWORK doubles

    normalize_rows<<<BDIM / 4, 256, 0, stream>>>(x, nf8, sq, counter);
    gram_hinge<<<NWORK, 256, 0, stream>>>(nf8, sq, y, part, counter, out);
}